// Round 9
// baseline (101.936 us; speedup 1.0000x reference)
//
#include <hip/hip_runtime.h>
#include <hip/hip_bf16.h>
#include <hip/hip_fp16.h>

// Problem constants
#define NXv 128
#define NYv 128
#define NZv 8
#define NVOX (NXv * NYv * NZv)   // 131072
#define NV 6
#define NC 64
#define HFv 116
#define WFv 200
#define PLANE (HFv * WFv)        // 23200

#define FT_BYTES ((size_t)NV * PLANE * NC * 2)   // 17,817,600 (bf16 channels-last)

// ---- helpers ---------------------------------------------------------------
typedef float v2f __attribute__((ext_vector_type(2)));

__device__ inline unsigned int f2bf(float f) {   // f32 -> bf16 bits, RNE
  unsigned int x = __float_as_uint(f);
  unsigned int r = x + 0x7fffu + ((x >> 16) & 1u);
  return (r >> 16) & 0xffffu;
}
__device__ inline v2f bfpair(unsigned int u) {   // packed bf16x2 -> float2
  v2f r;
  r.x = __uint_as_float(u << 16);
  r.y = __uint_as_float(u & 0xffff0000u);
  return r;
}

__device__ inline unsigned short f2h_bits(float f) {
  __half h = __float2half(f);
  return *reinterpret_cast<unsigned short*>(&h);
}
__device__ inline float h_bits2f(unsigned short u) {
  __half_raw r; r.x = u;
  __half h = *reinterpret_cast<__half*>(&r);
  return __half2float(h);
}

// ---------------------------------------------------------------------------
// K1: Transpose+convert [V][C][PLANE] f32 -> [V][PLANE][C] bf16 (packed).
// (At cold-BW floor: 53.4 MB compulsory ≈ 8.5 us.)
// ---------------------------------------------------------------------------
__global__ __launch_bounds__(256) void transpose_feat_bf16(
    const float* __restrict__ in, unsigned int* __restrict__ out32) {
  __shared__ float tile[64][65];                 // [pixel][channel]
  const int v  = blockIdx.y;
  const int p0 = blockIdx.x * 64;
  const float* src = in + (size_t)v * NC * PLANE;
  unsigned int* dst = out32 + (size_t)v * PLANE * (NC / 2);
  const int t = threadIdx.x;

#pragma unroll
  for (int i = 0; i < 4; ++i) {
    const int idx = i * 256 + t;
    const int c  = idx >> 4;
    const int p4 = idx & 15;
    const int pp = p0 + p4 * 4;
    if (pp < PLANE) {                            // PLANE%4==0 -> full float4 ok
      const float4 f = *(const float4*)(src + (size_t)c * PLANE + pp);
      tile[p4 * 4 + 0][c] = f.x;
      tile[p4 * 4 + 1][c] = f.y;
      tile[p4 * 4 + 2][c] = f.z;
      tile[p4 * 4 + 3][c] = f.w;
    }
  }
  __syncthreads();

#pragma unroll
  for (int i = 0; i < 2; ++i) {
    const int idx = i * 256 + t;
    const int p   = idx >> 3;
    const int c8  = idx & 7;
    const int pp  = p0 + p;
    if (pp < PLANE) {
      uint4 w;
      w.x = f2bf(tile[p][c8 * 8 + 0]) | (f2bf(tile[p][c8 * 8 + 1]) << 16);
      w.y = f2bf(tile[p][c8 * 8 + 2]) | (f2bf(tile[p][c8 * 8 + 3]) << 16);
      w.z = f2bf(tile[p][c8 * 8 + 4]) | (f2bf(tile[p][c8 * 8 + 5]) << 16);
      w.w = f2bf(tile[p][c8 * 8 + 6]) | (f2bf(tile[p][c8 * 8 + 7]) << 16);
      *(uint4*)(dst + (size_t)pp * 32 + c8 * 4) = w;
    }
  }
}

// ---------------------------------------------------------------------------
// K2: Fused projection + gather + coalesced store.
// Round-9 change: the harness's 268MB workspace-poison fills evict L2 AND L3
// every timed iteration, so K2's compulsory ft re-read was a SCATTERED cold-
// HBM fetch (~10us of the ~21.6us window time; warm REP = ~12us). Fix: a
// grid-wide SEQUENTIAL touch-read of ft at kernel start (coalesced, ~2.8us,
// overlapped with Phase A) pulls ft into the memory-side L3; Phase B's
// scattered taps then hit warm L3 instead of cold HBM.
// Phase A/B/C logic unchanged from round-8 (tap-split, f32 weights).
// ---------------------------------------------------------------------------
__global__ __launch_bounds__(256, 4) void gather_fused(
    const uint4* __restrict__ feat4,    // [V*PLANE][8] uint4 (64 bf16 ch)
    const float* __restrict__ points,
    const float* __restrict__ proj,
    float* __restrict__ out) {
  __shared__ uint2  pdl_pix[64][NV];          // 3KB  (p00|p10<<16, p01|p11<<16)
  __shared__ float4 pdl_w[64][NV];            // 6KB  (w00,w10,w01,w11) f32
  __shared__ unsigned short tile_h[64][66];   // 8.4KB f16 staging
  __shared__ unsigned int vmask[64];
  __shared__ float projl[96];

  const int bi   = blockIdx.x;
  const int t    = threadIdx.x;

  // ---- L3-warm prefetch: sequential stream of ft (L3 is cold every iter) ----
  {
    const int total = NV * PLANE * 8;         // 1,113,600 uint4 = 17.8MB
    for (int i = bi * 256 + t; i < total; i += 2048 * 256) {
      const uint4 p = feat4[i];
      asm volatile("" :: "v"(p.x), "v"(p.y), "v"(p.z), "v"(p.w));
    }
  }

  // spatial swizzle: XCD (~bi&7) owns two 32ix x 32iy squares
  const int xcd  = bi & 7;
  const int r    = bi >> 3;
  const int tid  = xcd * 2 + (r >> 7);
  const int q    = r & 127;
  const int ix   = (tid & 3) * 32 + (q & 31);
  const int iyg  = (tid >> 2) * 4 + (q >> 5);
  const int iy0g = iyg * 8;

  const int lane = t & 63;
  const int wave = t >> 6;

  if (t < 96) projl[t] = proj[t];
  if (t < 64) vmask[t] = 0u;
  __syncthreads();

  // ---- Phase A: all 256 threads; (slot, view-pair) per thread ----
  {
    const int slot = t & 63;
    const int vb   = t >> 6;
    const int j    = slot >> 3;
    const int iz   = slot & 7;
    const int n    = iz * (NXv * NYv) + (iy0g + j) * NXv + ix;

    const float x = points[n * 3 + 0];
    const float y = points[n * 3 + 1];
    const float z = points[n * 3 + 2];

#pragma unroll
    for (int vo = 0; vo < 2; ++vo) {
      const int v = vb + vo * 4;
      if (v < NV) {
        const float* M = projl + v * 16;
        const float cx = M[0] * x + M[1] * y + M[2]  * z + M[3];
        const float cy = M[4] * x + M[5] * y + M[6]  * z + M[7];
        const float cz = M[8] * x + M[9] * y + M[10] * z + M[11];

        const float dz = (fabsf(cz) > 1e-6f) ? cz : 1e-6f;
        const float u  = cx / dz;
        const float vv = cy / dz;

        const bool valid = (cz > 0.0f) && (u > 0.0f) && (u < 1600.0f) &&
                           (vv > 0.0f) && (vv < 928.0f);
        if (valid) {
          const float px = u  / 1600.0f * 200.0f - 0.5f;
          const float py = vv / 928.0f  * 116.0f - 0.5f;
          const float fx0 = floorf(px);
          const float fy0 = floorf(py);
          const float wx1 = px - fx0;
          const float wy1 = py - fy0;
          const float wx0 = 1.0f - wx1;
          const float wy0 = 1.0f - wy1;
          const int ix0 = (int)fx0;
          const int iy0 = (int)fy0;

          // per-tap in-bounds masks (reference semantics)
          const bool bx0 = (ix0 >= 0) && (ix0 < WFv);
          const bool bx1 = (ix0 + 1 >= 0) && (ix0 + 1 < WFv);
          const bool by0 = (iy0 >= 0) && (iy0 < HFv);
          const bool by1 = (iy0 + 1 >= 0) && (iy0 + 1 < HFv);

          // per-tap independently clamped coords (reference semantics)
          const int xc0 = min(max(ix0, 0), WFv - 1);
          const int xc1 = min(max(ix0 + 1, 0), WFv - 1);
          const int yc0 = min(max(iy0, 0), HFv - 1);
          const int yc1 = min(max(iy0 + 1, 0), HFv - 1);
          const unsigned int p00 = (unsigned int)(yc0 * WFv + xc0);
          const unsigned int p10 = (unsigned int)(yc0 * WFv + xc1);
          const unsigned int p01 = (unsigned int)(yc1 * WFv + xc0);
          const unsigned int p11 = (unsigned int)(yc1 * WFv + xc1);

          uint2 pix;
          pix.x = p00 | (p10 << 16);
          pix.y = p01 | (p11 << 16);
          float4 wv;
          wv.x = (bx0 && by0) ? wx0 * wy0 : 0.0f;
          wv.y = (bx1 && by0) ? wx1 * wy0 : 0.0f;
          wv.z = (bx0 && by1) ? wx0 * wy1 : 0.0f;
          wv.w = (bx1 && by1) ? wx1 * wy1 : 0.0f;
          pdl_pix[slot][v] = pix;
          pdl_w[slot][v]   = wv;
          atomicOr(&vmask[slot], 1u << v);
        } else {
          pdl_pix[slot][v] = (uint2){0u, 0u};
          pdl_w[slot][v]   = (float4){0.0f, 0.0f, 0.0f, 0.0f};
        }
      }
    }
  }
  __syncthreads();

  // ---- Phase B: tap-split branchless gather ----
  // lane = pg2(2b) | ch(3b) | half(1b):  4 points x 8 ch-chunks x 2 halves
  const int pg2  = lane >> 4;        // point within group of 4
  const int ch   = (lane >> 1) & 7;  // uint4 chunk (8 channels)
  const int half = lane & 1;         // 0: taps (p00,p10)  1: taps (p01,p11)

#pragma unroll
  for (int i = 0; i < 4; ++i) {
    const int gi = wave * 4 + i;     // 0..15
    const int jg = gi >> 3;          // 0..1
    const int iz = gi & 7;
    const int sl = (jg * 4 + pg2) * 8 + iz;   // same-z, adjacent-j group of 4

    const unsigned int m0 = vmask[sl];
    const int mycnt = __popc(m0);
    const int vdead = min(__builtin_ctz(~m0), NV - 1);

    int km = mycnt;
    km = max(km, __shfl_xor(km, 16));
    km = max(km, __shfl_xor(km, 32));   // wave-uniform max over the 4 points

    v2f acc2[4];
#pragma unroll
    for (int j2 = 0; j2 < 4; ++j2) acc2[j2] = (v2f){0.0f, 0.0f};

    unsigned int m = m0;
    for (int k = 0; k < km; ++k) {
      const bool live = (k < mycnt);
      const int v = live ? __builtin_ctz(m | 0x40u) : vdead;
      m &= m - 1;                       // m==0 stays 0

      const uint2 pix = pdl_pix[sl][v];
      const unsigned int ui = half ? pix.y : pix.x;
      const unsigned int pa = ui & 0xffffu;
      const unsigned int pb = ui >> 16;
      const v2f wp = *((const v2f*)&pdl_w[sl][v] + half);  // (wa, wb)

      const uint4* fb = feat4 + (size_t)v * (PLANE * 8) + ch;
      const uint4 qa = fb[(size_t)pa * 8];
      const uint4 qb = fb[(size_t)pb * 8];

      const v2f wva = (v2f){wp.x, wp.x};
      const v2f wvb = (v2f){wp.y, wp.y};

      acc2[0] = __builtin_elementwise_fma(wva, bfpair(qa.x), acc2[0]);
      acc2[1] = __builtin_elementwise_fma(wva, bfpair(qa.y), acc2[1]);
      acc2[2] = __builtin_elementwise_fma(wva, bfpair(qa.z), acc2[2]);
      acc2[3] = __builtin_elementwise_fma(wva, bfpair(qa.w), acc2[3]);

      acc2[0] = __builtin_elementwise_fma(wvb, bfpair(qb.x), acc2[0]);
      acc2[1] = __builtin_elementwise_fma(wvb, bfpair(qb.y), acc2[1]);
      acc2[2] = __builtin_elementwise_fma(wvb, bfpair(qb.z), acc2[2]);
      acc2[3] = __builtin_elementwise_fma(wvb, bfpair(qb.w), acc2[3]);
    }

    // merge tap-halves: partner lane = lane ^ 1
#pragma unroll
    for (int j2 = 0; j2 < 4; ++j2) {
      acc2[j2].x += __shfl_xor(acc2[j2].x, 1);
      acc2[j2].y += __shfl_xor(acc2[j2].y, 1);
    }

    if (half == 0) {
      const float inv = (mycnt > 0) ? 1.0f / (float)mycnt : 0.0f;
#pragma unroll
      for (int j2 = 0; j2 < 4; ++j2) {
        const unsigned int pk =
            (unsigned int)f2h_bits(acc2[j2].x * inv) |
            ((unsigned int)f2h_bits(acc2[j2].y * inv) << 16);
        *(unsigned int*)&tile_h[sl][ch * 8 + j2 * 2] = pk;
      }
    }
  }

  __syncthreads();

  // ---- Phase C: nontemporal coalesced store ----
  const size_t obase = (size_t)ix * (NYv * NZv) + (size_t)iy0g * NZv + lane;
#pragma unroll
  for (int i = 0; i < 16; ++i) {
    const int c = i * 4 + wave;
    const float val = h_bits2f(tile_h[lane][c]);
    __builtin_nontemporal_store(val, &out[(size_t)c * NVOX + obase]);
  }
}

// ---------------------------------------------------------------------------
// Fallback: direct channel-major sampling (no workspace).
// ---------------------------------------------------------------------------
__global__ __launch_bounds__(256) void sample_fallback(
    const float* __restrict__ feat,
    const float* __restrict__ points,
    const float* __restrict__ proj,
    float* __restrict__ out) {
  const int wave = threadIdx.x >> 6;
  const int lane = threadIdx.x & 63;
  const int n = blockIdx.x * 4 + wave;

  const float x = points[n * 3 + 0];
  const float y = points[n * 3 + 1];
  const float z = points[n * 3 + 2];

  float acc = 0.0f;
  int cnt = 0;

#pragma unroll
  for (int v = 0; v < NV; ++v) {
    const float* M = proj + v * 16;
    const float cx = M[0] * x + M[1] * y + M[2]  * z + M[3];
    const float cy = M[4] * x + M[5] * y + M[6]  * z + M[7];
    const float cz = M[8] * x + M[9] * y + M[10] * z + M[11];
    const float dz = (fabsf(cz) > 1e-6f) ? cz : 1e-6f;
    const float u  = cx / dz;
    const float vv = cy / dz;
    const bool valid = (cz > 0.0f) && (u > 0.0f) && (u < 1600.0f) &&
                       (vv > 0.0f) && (vv < 928.0f);
    if (!valid) continue;
    cnt++;
    const float px = u  / 1600.0f * 200.0f - 0.5f;
    const float py = vv / 928.0f  * 116.0f - 0.5f;
    const float fx0 = floorf(px);
    const float fy0 = floorf(py);
    const float wx1 = px - fx0;
    const float wy1 = py - fy0;
    const float wx0 = 1.0f - wx1;
    const float wy0 = 1.0f - wy1;
    const int ix0 = (int)fx0;
    const int iy0 = (int)fy0;
    const float w00 = wx0 * wy0, w10 = wx1 * wy0, w01 = wx0 * wy1, w11 = wx1 * wy1;
    const float* basev = feat + ((size_t)v * NC + lane) * PLANE;
    auto tap = [&](int xi, int yi, float w) {
      if (xi >= 0 && xi < WFv && yi >= 0 && yi < HFv)
        acc += w * basev[yi * WFv + xi];
    };
    tap(ix0,     iy0,     w00);
    tap(ix0 + 1, iy0,     w10);
    tap(ix0,     iy0 + 1, w01);
    tap(ix0 + 1, iy0 + 1, w11);
  }

  const float scale = (cnt > 0) ? (1.0f / (float)cnt) : 0.0f;
  const int iz  = n >> 14;
  const int rem = n & 16383;
  const int iy  = rem >> 7;
  const int ixx = rem & 127;
  out[(((size_t)lane * NXv + ixx) * NYv + iy) * NZv + iz] = acc * scale;
}

extern "C" void kernel_launch(void* const* d_in, const int* in_sizes, int n_in,
                              void* d_out, int out_size, void* d_ws, size_t ws_size,
                              hipStream_t stream) {
  const float* x_fov  = (const float*)d_in[0];  // [1,6,64,116,200] f32
  const float* points = (const float*)d_in[1];  // [131072,3] f32
  const float* proj   = (const float*)d_in[2];  // [6,4,4] f32
  float* out = (float*)d_out;                   // [1,64,128,128,8] f32

  if (ws_size >= FT_BYTES) {
    unsigned int* ft = (unsigned int*)d_ws;
    dim3 tgrid((PLANE + 63) / 64, NV);
    transpose_feat_bf16<<<tgrid, 256, 0, stream>>>(x_fov, ft);
    gather_fused<<<NXv * NYv / 8, 256, 0, stream>>>((const uint4*)ft, points, proj, out);
  } else {
    sample_fallback<<<NVOX / 4, 256, 0, stream>>>(x_fov, points, proj, out);
  }
}

// Round 10
// 100.580 us; speedup vs baseline: 1.0135x; 1.0135x over previous
//
#include <hip/hip_runtime.h>
#include <hip/hip_cooperative_groups.h>
#include <hip/hip_bf16.h>
#include <hip/hip_fp16.h>

namespace cg = cooperative_groups;

// Problem constants
#define NXv 128
#define NYv 128
#define NZv 8
#define NVOX (NXv * NYv * NZv)   // 131072
#define NV 6
#define NC 64
#define HFv 116
#define WFv 200
#define PLANE (HFv * WFv)        // 23200
#define K1_TILES 2178            // ceil(PLANE/64)*NV
#define COOP_GRID 2048

#define FT_BYTES ((size_t)NV * PLANE * NC * 2)   // 17,817,600 (bf16 channels-last)

// ---- helpers ---------------------------------------------------------------
typedef float v2f __attribute__((ext_vector_type(2)));

__device__ inline unsigned int f2bf(float f) {   // f32 -> bf16 bits, RNE
  unsigned int x = __float_as_uint(f);
  unsigned int r = x + 0x7fffu + ((x >> 16) & 1u);
  return (r >> 16) & 0xffffu;
}
__device__ inline v2f bfpair(unsigned int u) {   // packed bf16x2 -> float2
  v2f r;
  r.x = __uint_as_float(u << 16);
  r.y = __uint_as_float(u & 0xffff0000u);
  return r;
}

__device__ inline unsigned short f2h_bits(float f) {
  __half h = __float2half(f);
  return *reinterpret_cast<unsigned short*>(&h);
}
__device__ inline float h_bits2f(unsigned short u) {
  __half_raw r; r.x = u;
  __half h = *reinterpret_cast<__half*>(&r);
  return __half2float(h);
}

// ---------------------------------------------------------------------------
// Device-side phase bodies (shared by the cooperative kernel and the
// two-kernel fallback) are written inline in each kernel to keep codegen
// contexts independent (rule: co-compiled variants perturb regalloc).
// ---------------------------------------------------------------------------

// ---------------------------------------------------------------------------
// K1 (fallback): Transpose+convert [V][C][PLANE] f32 -> [V][PLANE][C] bf16.
// ---------------------------------------------------------------------------
__global__ __launch_bounds__(256) void transpose_feat_bf16(
    const float* __restrict__ in, unsigned int* __restrict__ out32) {
  __shared__ float tile[64][65];                 // [pixel][channel]
  const int v  = blockIdx.y;
  const int p0 = blockIdx.x * 64;
  const float* src = in + (size_t)v * NC * PLANE;
  unsigned int* dst = out32 + (size_t)v * PLANE * (NC / 2);
  const int t = threadIdx.x;

#pragma unroll
  for (int i = 0; i < 4; ++i) {
    const int idx = i * 256 + t;
    const int c  = idx >> 4;
    const int p4 = idx & 15;
    const int pp = p0 + p4 * 4;
    if (pp < PLANE) {                            // PLANE%4==0 -> full float4 ok
      const float4 f = *(const float4*)(src + (size_t)c * PLANE + pp);
      tile[p4 * 4 + 0][c] = f.x;
      tile[p4 * 4 + 1][c] = f.y;
      tile[p4 * 4 + 2][c] = f.z;
      tile[p4 * 4 + 3][c] = f.w;
    }
  }
  __syncthreads();

#pragma unroll
  for (int i = 0; i < 2; ++i) {
    const int idx = i * 256 + t;
    const int p   = idx >> 3;
    const int c8  = idx & 7;
    const int pp  = p0 + p;
    if (pp < PLANE) {
      uint4 w;
      w.x = f2bf(tile[p][c8 * 8 + 0]) | (f2bf(tile[p][c8 * 8 + 1]) << 16);
      w.y = f2bf(tile[p][c8 * 8 + 2]) | (f2bf(tile[p][c8 * 8 + 3]) << 16);
      w.z = f2bf(tile[p][c8 * 8 + 4]) | (f2bf(tile[p][c8 * 8 + 5]) << 16);
      w.w = f2bf(tile[p][c8 * 8 + 6]) | (f2bf(tile[p][c8 * 8 + 7]) << 16);
      *(uint4*)(dst + (size_t)pp * 32 + c8 * 4) = w;
    }
  }
}

// ---------------------------------------------------------------------------
// K2 (fallback): r8 gather, prefetch removed (r9 showed it was pure overhead).
// ---------------------------------------------------------------------------
__global__ __launch_bounds__(256, 4) void gather_fused(
    const uint4* __restrict__ feat4,
    const float* __restrict__ points,
    const float* __restrict__ proj,
    float* __restrict__ out) {
  __shared__ uint2  pdl_pix[64][NV];
  __shared__ float4 pdl_w[64][NV];
  __shared__ unsigned short tile_h[64][66];
  __shared__ unsigned int vmask[64];
  __shared__ float projl[96];

  const int bi   = blockIdx.x;
  const int xcd  = bi & 7;
  const int r    = bi >> 3;
  const int tid  = xcd * 2 + (r >> 7);
  const int q    = r & 127;
  const int ix   = (tid & 3) * 32 + (q & 31);
  const int iyg  = (tid >> 2) * 4 + (q >> 5);
  const int iy0g = iyg * 8;

  const int t    = threadIdx.x;
  const int lane = t & 63;
  const int wave = t >> 6;

  if (t < 96) projl[t] = proj[t];
  if (t < 64) vmask[t] = 0u;
  __syncthreads();

  // ---- Phase A ----
  {
    const int slot = t & 63;
    const int vb   = t >> 6;
    const int j    = slot >> 3;
    const int iz   = slot & 7;
    const int n    = iz * (NXv * NYv) + (iy0g + j) * NXv + ix;

    const float x = points[n * 3 + 0];
    const float y = points[n * 3 + 1];
    const float z = points[n * 3 + 2];

#pragma unroll
    for (int vo = 0; vo < 2; ++vo) {
      const int v = vb + vo * 4;
      if (v < NV) {
        const float* M = projl + v * 16;
        const float cx = M[0] * x + M[1] * y + M[2]  * z + M[3];
        const float cy = M[4] * x + M[5] * y + M[6]  * z + M[7];
        const float cz = M[8] * x + M[9] * y + M[10] * z + M[11];

        const float dz = (fabsf(cz) > 1e-6f) ? cz : 1e-6f;
        const float u  = cx / dz;
        const float vv = cy / dz;

        const bool valid = (cz > 0.0f) && (u > 0.0f) && (u < 1600.0f) &&
                           (vv > 0.0f) && (vv < 928.0f);
        if (valid) {
          const float px = u  / 1600.0f * 200.0f - 0.5f;
          const float py = vv / 928.0f  * 116.0f - 0.5f;
          const float fx0 = floorf(px);
          const float fy0 = floorf(py);
          const float wx1 = px - fx0;
          const float wy1 = py - fy0;
          const float wx0 = 1.0f - wx1;
          const float wy0 = 1.0f - wy1;
          const int ix0 = (int)fx0;
          const int iy0 = (int)fy0;

          const bool bx0 = (ix0 >= 0) && (ix0 < WFv);
          const bool bx1 = (ix0 + 1 >= 0) && (ix0 + 1 < WFv);
          const bool by0 = (iy0 >= 0) && (iy0 < HFv);
          const bool by1 = (iy0 + 1 >= 0) && (iy0 + 1 < HFv);

          const int xc0 = min(max(ix0, 0), WFv - 1);
          const int xc1 = min(max(ix0 + 1, 0), WFv - 1);
          const int yc0 = min(max(iy0, 0), HFv - 1);
          const int yc1 = min(max(iy0 + 1, 0), HFv - 1);
          const unsigned int p00 = (unsigned int)(yc0 * WFv + xc0);
          const unsigned int p10 = (unsigned int)(yc0 * WFv + xc1);
          const unsigned int p01 = (unsigned int)(yc1 * WFv + xc0);
          const unsigned int p11 = (unsigned int)(yc1 * WFv + xc1);

          uint2 pix;
          pix.x = p00 | (p10 << 16);
          pix.y = p01 | (p11 << 16);
          float4 wv;
          wv.x = (bx0 && by0) ? wx0 * wy0 : 0.0f;
          wv.y = (bx1 && by0) ? wx1 * wy0 : 0.0f;
          wv.z = (bx0 && by1) ? wx0 * wy1 : 0.0f;
          wv.w = (bx1 && by1) ? wx1 * wy1 : 0.0f;
          pdl_pix[slot][v] = pix;
          pdl_w[slot][v]   = wv;
          atomicOr(&vmask[slot], 1u << v);
        } else {
          pdl_pix[slot][v] = (uint2){0u, 0u};
          pdl_w[slot][v]   = (float4){0.0f, 0.0f, 0.0f, 0.0f};
        }
      }
    }
  }
  __syncthreads();

  // ---- Phase B ----
  const int pg2  = lane >> 4;
  const int ch   = (lane >> 1) & 7;
  const int half = lane & 1;

#pragma unroll
  for (int i = 0; i < 4; ++i) {
    const int gi = wave * 4 + i;
    const int jg = gi >> 3;
    const int iz = gi & 7;
    const int sl = (jg * 4 + pg2) * 8 + iz;

    const unsigned int m0 = vmask[sl];
    const int mycnt = __popc(m0);
    const int vdead = min(__builtin_ctz(~m0), NV - 1);

    int km = mycnt;
    km = max(km, __shfl_xor(km, 16));
    km = max(km, __shfl_xor(km, 32));

    v2f acc2[4];
#pragma unroll
    for (int j2 = 0; j2 < 4; ++j2) acc2[j2] = (v2f){0.0f, 0.0f};

    unsigned int m = m0;
    for (int k = 0; k < km; ++k) {
      const bool live = (k < mycnt);
      const int v = live ? __builtin_ctz(m | 0x40u) : vdead;
      m &= m - 1;

      const uint2 pix = pdl_pix[sl][v];
      const unsigned int ui = half ? pix.y : pix.x;
      const unsigned int pa = ui & 0xffffu;
      const unsigned int pb = ui >> 16;
      const v2f wp = *((const v2f*)&pdl_w[sl][v] + half);

      const uint4* fb = feat4 + (size_t)v * (PLANE * 8) + ch;
      const uint4 qa = fb[(size_t)pa * 8];
      const uint4 qb = fb[(size_t)pb * 8];

      const v2f wva = (v2f){wp.x, wp.x};
      const v2f wvb = (v2f){wp.y, wp.y};

      acc2[0] = __builtin_elementwise_fma(wva, bfpair(qa.x), acc2[0]);
      acc2[1] = __builtin_elementwise_fma(wva, bfpair(qa.y), acc2[1]);
      acc2[2] = __builtin_elementwise_fma(wva, bfpair(qa.z), acc2[2]);
      acc2[3] = __builtin_elementwise_fma(wva, bfpair(qa.w), acc2[3]);

      acc2[0] = __builtin_elementwise_fma(wvb, bfpair(qb.x), acc2[0]);
      acc2[1] = __builtin_elementwise_fma(wvb, bfpair(qb.y), acc2[1]);
      acc2[2] = __builtin_elementwise_fma(wvb, bfpair(qb.z), acc2[2]);
      acc2[3] = __builtin_elementwise_fma(wvb, bfpair(qb.w), acc2[3]);
    }

#pragma unroll
    for (int j2 = 0; j2 < 4; ++j2) {
      acc2[j2].x += __shfl_xor(acc2[j2].x, 1);
      acc2[j2].y += __shfl_xor(acc2[j2].y, 1);
    }

    if (half == 0) {
      const float inv = (mycnt > 0) ? 1.0f / (float)mycnt : 0.0f;
#pragma unroll
      for (int j2 = 0; j2 < 4; ++j2) {
        const unsigned int pk =
            (unsigned int)f2h_bits(acc2[j2].x * inv) |
            ((unsigned int)f2h_bits(acc2[j2].y * inv) << 16);
        *(unsigned int*)&tile_h[sl][ch * 8 + j2 * 2] = pk;
      }
    }
  }

  __syncthreads();

  // ---- Phase C ----
  const size_t obase = (size_t)ix * (NYv * NZv) + (size_t)iy0g * NZv + lane;
#pragma unroll
  for (int i = 0; i < 16; ++i) {
    const int c = i * 4 + wave;
    const float val = h_bits2f(tile_h[lane][c]);
    __builtin_nontemporal_store(val, &out[(size_t)c * NVOX + obase]);
  }
}

// ---------------------------------------------------------------------------
// COOPERATIVE fused kernel: PhaseA -> transpose(grid-stride) -> fence ->
// grid.sync -> PhaseB -> PhaseC. Removes the inter-kernel L2 flush + launch
// ramp between K1 and K2. LDS union keeps block at ~18.3KB -> 8 blocks/CU.
// Cross-XCD ft visibility: __threadfence() (agent scope, writes back dirty
// L2) before grid.sync; reader L2s hold no stale ft lines (previous kernel's
// end-of-kernel flush invalidated the poison fill's lines).
// ---------------------------------------------------------------------------
__global__ __launch_bounds__(256, 4) void fused_coop(
    const float* __restrict__ x_fov,
    unsigned int* __restrict__ ft,
    const float* __restrict__ points,
    const float* __restrict__ proj,
    float* __restrict__ out) {
  __shared__ float projl[96];
  __shared__ unsigned int vmask[64];
  __shared__ uint2 pdl_pix[64][NV];
  __shared__ float4 pdl_w[64][NV];
  __shared__ __align__(16) unsigned char scratch[8448];  // tile / tile_h union

  const int bi   = blockIdx.x;
  const int t    = threadIdx.x;
  const int lane = t & 63;
  const int wave = t >> 6;

  // K2 spatial swizzle (identical to gather_fused)
  const int xcd  = bi & 7;
  const int r    = bi >> 3;
  const int tid  = xcd * 2 + (r >> 7);
  const int q    = r & 127;
  const int ix   = (tid & 3) * 32 + (q & 31);
  const int iyg  = (tid >> 2) * 4 + (q >> 5);
  const int iy0g = iyg * 8;

  if (t < 96) projl[t] = proj[t];
  if (t < 64) vmask[t] = 0u;
  __syncthreads();

  // ---- Phase A: projections for this block's voxel group (no ft needed) ----
  {
    const int slot = t & 63;
    const int vb   = t >> 6;
    const int j    = slot >> 3;
    const int iz   = slot & 7;
    const int n    = iz * (NXv * NYv) + (iy0g + j) * NXv + ix;

    const float x = points[n * 3 + 0];
    const float y = points[n * 3 + 1];
    const float z = points[n * 3 + 2];

#pragma unroll
    for (int vo = 0; vo < 2; ++vo) {
      const int v = vb + vo * 4;
      if (v < NV) {
        const float* M = projl + v * 16;
        const float cx = M[0] * x + M[1] * y + M[2]  * z + M[3];
        const float cy = M[4] * x + M[5] * y + M[6]  * z + M[7];
        const float cz = M[8] * x + M[9] * y + M[10] * z + M[11];

        const float dz = (fabsf(cz) > 1e-6f) ? cz : 1e-6f;
        const float u  = cx / dz;
        const float vv = cy / dz;

        const bool valid = (cz > 0.0f) && (u > 0.0f) && (u < 1600.0f) &&
                           (vv > 0.0f) && (vv < 928.0f);
        if (valid) {
          const float px = u  / 1600.0f * 200.0f - 0.5f;
          const float py = vv / 928.0f  * 116.0f - 0.5f;
          const float fx0 = floorf(px);
          const float fy0 = floorf(py);
          const float wx1 = px - fx0;
          const float wy1 = py - fy0;
          const float wx0 = 1.0f - wx1;
          const float wy0 = 1.0f - wy1;
          const int ix0 = (int)fx0;
          const int iy0 = (int)fy0;

          const bool bx0 = (ix0 >= 0) && (ix0 < WFv);
          const bool bx1 = (ix0 + 1 >= 0) && (ix0 + 1 < WFv);
          const bool by0 = (iy0 >= 0) && (iy0 < HFv);
          const bool by1 = (iy0 + 1 >= 0) && (iy0 + 1 < HFv);

          const int xc0 = min(max(ix0, 0), WFv - 1);
          const int xc1 = min(max(ix0 + 1, 0), WFv - 1);
          const int yc0 = min(max(iy0, 0), HFv - 1);
          const int yc1 = min(max(iy0 + 1, 0), HFv - 1);
          const unsigned int p00 = (unsigned int)(yc0 * WFv + xc0);
          const unsigned int p10 = (unsigned int)(yc0 * WFv + xc1);
          const unsigned int p01 = (unsigned int)(yc1 * WFv + xc0);
          const unsigned int p11 = (unsigned int)(yc1 * WFv + xc1);

          uint2 pix;
          pix.x = p00 | (p10 << 16);
          pix.y = p01 | (p11 << 16);
          float4 wv;
          wv.x = (bx0 && by0) ? wx0 * wy0 : 0.0f;
          wv.y = (bx1 && by0) ? wx1 * wy0 : 0.0f;
          wv.z = (bx0 && by1) ? wx0 * wy1 : 0.0f;
          wv.w = (bx1 && by1) ? wx1 * wy1 : 0.0f;
          pdl_pix[slot][v] = pix;
          pdl_w[slot][v]   = wv;
          atomicOr(&vmask[slot], 1u << v);
        } else {
          pdl_pix[slot][v] = (uint2){0u, 0u};
          pdl_w[slot][v]   = (float4){0.0f, 0.0f, 0.0f, 0.0f};
        }
      }
    }
  }
  __syncthreads();

  // ---- K1-phase: transpose+convert, grid-stride over 2178 tiles ----
  {
    float (*tile)[65] = (float(*)[65])scratch;   // [32][65] = 8320B
    for (int tl = bi; tl < K1_TILES; tl += COOP_GRID) {
      const int v  = tl / 363;
      const int tp = tl - v * 363;
      const float* src = x_fov + (size_t)v * NC * PLANE;
      unsigned int* dst = ft + (size_t)v * PLANE * 32;

#pragma unroll
      for (int h = 0; h < 2; ++h) {
        const int p0 = tp * 64 + h * 32;
#pragma unroll
        for (int i = 0; i < 2; ++i) {
          const int idx = i * 256 + t;
          const int c  = idx >> 3;         // 0..63
          const int p4 = idx & 7;          // 0..7 pixel-quads
          const int pp = p0 + p4 * 4;
          if (pp < PLANE) {
            const float4 f = *(const float4*)(src + (size_t)c * PLANE + pp);
            tile[p4 * 4 + 0][c] = f.x;
            tile[p4 * 4 + 1][c] = f.y;
            tile[p4 * 4 + 2][c] = f.z;
            tile[p4 * 4 + 3][c] = f.w;
          }
        }
        __syncthreads();
        {
          const int p  = t >> 3;           // 0..31
          const int c8 = t & 7;
          const int pp = p0 + p;
          if (pp < PLANE) {
            uint4 w;
            w.x = f2bf(tile[p][c8 * 8 + 0]) | (f2bf(tile[p][c8 * 8 + 1]) << 16);
            w.y = f2bf(tile[p][c8 * 8 + 2]) | (f2bf(tile[p][c8 * 8 + 3]) << 16);
            w.z = f2bf(tile[p][c8 * 8 + 4]) | (f2bf(tile[p][c8 * 8 + 5]) << 16);
            w.w = f2bf(tile[p][c8 * 8 + 6]) | (f2bf(tile[p][c8 * 8 + 7]) << 16);
            *(uint4*)(dst + (size_t)pp * 32 + c8 * 4) = w;
          }
        }
        __syncthreads();
      }
    }
  }

  __threadfence();            // agent-scope release: drain dirty ft L2 lines
  cg::this_grid().sync();     // all ft written & visible device-wide

  // ---- Phase B: tap-split branchless gather ----
  const uint4* feat4 = (const uint4*)ft;
  unsigned short (*tile_h)[66] = (unsigned short(*)[66])scratch;  // 8448B

  const int pg2  = lane >> 4;
  const int ch   = (lane >> 1) & 7;
  const int half = lane & 1;

#pragma unroll
  for (int i = 0; i < 4; ++i) {
    const int gi = wave * 4 + i;
    const int jg = gi >> 3;
    const int iz = gi & 7;
    const int sl = (jg * 4 + pg2) * 8 + iz;

    const unsigned int m0 = vmask[sl];
    const int mycnt = __popc(m0);
    const int vdead = min(__builtin_ctz(~m0), NV - 1);

    int km = mycnt;
    km = max(km, __shfl_xor(km, 16));
    km = max(km, __shfl_xor(km, 32));

    v2f acc2[4];
#pragma unroll
    for (int j2 = 0; j2 < 4; ++j2) acc2[j2] = (v2f){0.0f, 0.0f};

    unsigned int m = m0;
    for (int k = 0; k < km; ++k) {
      const bool live = (k < mycnt);
      const int v = live ? __builtin_ctz(m | 0x40u) : vdead;
      m &= m - 1;

      const uint2 pix = pdl_pix[sl][v];
      const unsigned int ui = half ? pix.y : pix.x;
      const unsigned int pa = ui & 0xffffu;
      const unsigned int pb = ui >> 16;
      const v2f wp = *((const v2f*)&pdl_w[sl][v] + half);

      const uint4* fb = feat4 + (size_t)v * (PLANE * 8) + ch;
      const uint4 qa = fb[(size_t)pa * 8];
      const uint4 qb = fb[(size_t)pb * 8];

      const v2f wva = (v2f){wp.x, wp.x};
      const v2f wvb = (v2f){wp.y, wp.y};

      acc2[0] = __builtin_elementwise_fma(wva, bfpair(qa.x), acc2[0]);
      acc2[1] = __builtin_elementwise_fma(wva, bfpair(qa.y), acc2[1]);
      acc2[2] = __builtin_elementwise_fma(wva, bfpair(qa.z), acc2[2]);
      acc2[3] = __builtin_elementwise_fma(wva, bfpair(qa.w), acc2[3]);

      acc2[0] = __builtin_elementwise_fma(wvb, bfpair(qb.x), acc2[0]);
      acc2[1] = __builtin_elementwise_fma(wvb, bfpair(qb.y), acc2[1]);
      acc2[2] = __builtin_elementwise_fma(wvb, bfpair(qb.z), acc2[2]);
      acc2[3] = __builtin_elementwise_fma(wvb, bfpair(qb.w), acc2[3]);
    }

#pragma unroll
    for (int j2 = 0; j2 < 4; ++j2) {
      acc2[j2].x += __shfl_xor(acc2[j2].x, 1);
      acc2[j2].y += __shfl_xor(acc2[j2].y, 1);
    }

    if (half == 0) {
      const float inv = (mycnt > 0) ? 1.0f / (float)mycnt : 0.0f;
#pragma unroll
      for (int j2 = 0; j2 < 4; ++j2) {
        const unsigned int pk =
            (unsigned int)f2h_bits(acc2[j2].x * inv) |
            ((unsigned int)f2h_bits(acc2[j2].y * inv) << 16);
        *(unsigned int*)&tile_h[sl][ch * 8 + j2 * 2] = pk;
      }
    }
  }

  __syncthreads();

  // ---- Phase C: nontemporal coalesced store ----
  const size_t obase = (size_t)ix * (NYv * NZv) + (size_t)iy0g * NZv + lane;
#pragma unroll
  for (int i = 0; i < 16; ++i) {
    const int c = i * 4 + wave;
    const float val = h_bits2f(tile_h[lane][c]);
    __builtin_nontemporal_store(val, &out[(size_t)c * NVOX + obase]);
  }
}

// ---------------------------------------------------------------------------
// Fallback: direct channel-major sampling (no workspace).
// ---------------------------------------------------------------------------
__global__ __launch_bounds__(256) void sample_fallback(
    const float* __restrict__ feat,
    const float* __restrict__ points,
    const float* __restrict__ proj,
    float* __restrict__ out) {
  const int wave = threadIdx.x >> 6;
  const int lane = threadIdx.x & 63;
  const int n = blockIdx.x * 4 + wave;

  const float x = points[n * 3 + 0];
  const float y = points[n * 3 + 1];
  const float z = points[n * 3 + 2];

  float acc = 0.0f;
  int cnt = 0;

#pragma unroll
  for (int v = 0; v < NV; ++v) {
    const float* M = proj + v * 16;
    const float cx = M[0] * x + M[1] * y + M[2]  * z + M[3];
    const float cy = M[4] * x + M[5] * y + M[6]  * z + M[7];
    const float cz = M[8] * x + M[9] * y + M[10] * z + M[11];
    const float dz = (fabsf(cz) > 1e-6f) ? cz : 1e-6f;
    const float u  = cx / dz;
    const float vv = cy / dz;
    const bool valid = (cz > 0.0f) && (u > 0.0f) && (u < 1600.0f) &&
                       (vv > 0.0f) && (vv < 928.0f);
    if (!valid) continue;
    cnt++;
    const float px = u  / 1600.0f * 200.0f - 0.5f;
    const float py = vv / 928.0f  * 116.0f - 0.5f;
    const float fx0 = floorf(px);
    const float fy0 = floorf(py);
    const float wx1 = px - fx0;
    const float wy1 = py - fy0;
    const float wx0 = 1.0f - wx1;
    const float wy0 = 1.0f - wy1;
    const int ix0 = (int)fx0;
    const int iy0 = (int)fy0;
    const float w00 = wx0 * wy0, w10 = wx1 * wy0, w01 = wx0 * wy1, w11 = wx1 * wy1;
    const float* basev = feat + ((size_t)v * NC + lane) * PLANE;
    auto tap = [&](int xi, int yi, float w) {
      if (xi >= 0 && xi < WFv && yi >= 0 && yi < HFv)
        acc += w * basev[yi * WFv + xi];
    };
    tap(ix0,     iy0,     w00);
    tap(ix0 + 1, iy0,     w10);
    tap(ix0,     iy0 + 1, w01);
    tap(ix0 + 1, iy0 + 1, w11);
  }

  const float scale = (cnt > 0) ? (1.0f / (float)cnt) : 0.0f;
  const int iz  = n >> 14;
  const int rem = n & 16383;
  const int iy  = rem >> 7;
  const int ixx = rem & 127;
  out[(((size_t)lane * NXv + ixx) * NYv + iy) * NZv + iz] = acc * scale;
}

extern "C" void kernel_launch(void* const* d_in, const int* in_sizes, int n_in,
                              void* d_out, int out_size, void* d_ws, size_t ws_size,
                              hipStream_t stream) {
  const float* x_fov  = (const float*)d_in[0];  // [1,6,64,116,200] f32
  const float* points = (const float*)d_in[1];  // [131072,3] f32
  const float* proj   = (const float*)d_in[2];  // [6,4,4] f32
  float* out = (float*)d_out;                   // [1,64,128,128,8] f32

  if (ws_size >= FT_BYTES) {
    unsigned int* ft = (unsigned int*)d_ws;

    // Cooperative path requires all 2048 blocks co-resident (8 blocks/CU on
    // 256 CUs). Query once; fall back to the proven two-kernel path if the
    // compiler's VGPR/LDS allocation doesn't admit it, or if the launch fails.
    static int coop_state = -1;   // -1 unknown, 0 off, 1 on
    if (coop_state == -1) {
      int nb = 0;
      hipError_t qe = hipOccupancyMaxActiveBlocksPerMultiprocessor(
          &nb, (const void*)fused_coop, 256, 0);
      coop_state = (qe == hipSuccess && nb >= 8) ? 1 : 0;
    }

    if (coop_state == 1) {
      void* args[] = {(void*)&x_fov, (void*)&ft, (void*)&points,
                      (void*)&proj, (void*)&out};
      hipError_t le = hipLaunchCooperativeKernel(
          (const void*)fused_coop, dim3(COOP_GRID), dim3(256), args, 0, stream);
      if (le == hipSuccess) return;
      (void)hipGetLastError();     // clear and fall through to two-kernel path
      coop_state = 0;
    }

    dim3 tgrid((PLANE + 63) / 64, NV);
    transpose_feat_bf16<<<tgrid, 256, 0, stream>>>(x_fov, ft);
    gather_fused<<<NXv * NYv / 8, 256, 0, stream>>>((const uint4*)ft, points, proj, out);
  } else {
    sample_fallback<<<NVOX / 4, 256, 0, stream>>>(x_fov, points, proj, out);
  }
}

// Round 11
// 99.508 us; speedup vs baseline: 1.0244x; 1.0108x over previous
//
#include <hip/hip_runtime.h>
#include <hip/hip_bf16.h>
#include <hip/hip_fp16.h>

// Problem constants
#define NXv 128
#define NYv 128
#define NZv 8
#define NVOX (NXv * NYv * NZv)   // 131072
#define NV 6
#define NC 64
#define HFv 116
#define WFv 200
#define PLANE (HFv * WFv)        // 23200

#define FT_BYTES ((size_t)NV * PLANE * NC * 2)   // 17,817,600 (bf16 channels-last)

// ---- helpers ---------------------------------------------------------------
typedef float v2f __attribute__((ext_vector_type(2)));
typedef float v4f __attribute__((ext_vector_type(4)));

__device__ inline unsigned int f2bf(float f) {   // f32 -> bf16 bits, RNE
  unsigned int x = __float_as_uint(f);
  unsigned int r = x + 0x7fffu + ((x >> 16) & 1u);
  return (r >> 16) & 0xffffu;
}
__device__ inline v2f bfpair(unsigned int u) {   // packed bf16x2 -> float2
  v2f r;
  r.x = __uint_as_float(u << 16);
  r.y = __uint_as_float(u & 0xffff0000u);
  return r;
}

__device__ inline unsigned short f2h_bits(float f) {
  __half h = __float2half(f);
  return *reinterpret_cast<unsigned short*>(&h);
}
__device__ inline float h_bits2f(unsigned short u) {
  __half_raw r; r.x = u;
  __half h = *reinterpret_cast<__half*>(&r);
  return __half2float(h);
}

// ---------------------------------------------------------------------------
// K1: Transpose+convert [V][C][PLANE] f32 -> [V][PLANE][C] bf16 (packed).
// (At cold-BW floor: 53.4 MB compulsory ≈ 8.5 us.)
// ---------------------------------------------------------------------------
__global__ __launch_bounds__(256) void transpose_feat_bf16(
    const float* __restrict__ in, unsigned int* __restrict__ out32) {
  __shared__ float tile[64][65];                 // [pixel][channel]
  const int v  = blockIdx.y;
  const int p0 = blockIdx.x * 64;
  const float* src = in + (size_t)v * NC * PLANE;
  unsigned int* dst = out32 + (size_t)v * PLANE * (NC / 2);
  const int t = threadIdx.x;

#pragma unroll
  for (int i = 0; i < 4; ++i) {
    const int idx = i * 256 + t;
    const int c  = idx >> 4;
    const int p4 = idx & 15;
    const int pp = p0 + p4 * 4;
    if (pp < PLANE) {                            // PLANE%4==0 -> full float4 ok
      const float4 f = *(const float4*)(src + (size_t)c * PLANE + pp);
      tile[p4 * 4 + 0][c] = f.x;
      tile[p4 * 4 + 1][c] = f.y;
      tile[p4 * 4 + 2][c] = f.z;
      tile[p4 * 4 + 3][c] = f.w;
    }
  }
  __syncthreads();

#pragma unroll
  for (int i = 0; i < 2; ++i) {
    const int idx = i * 256 + t;
    const int p   = idx >> 3;
    const int c8  = idx & 7;
    const int pp  = p0 + p;
    if (pp < PLANE) {
      uint4 w;
      w.x = f2bf(tile[p][c8 * 8 + 0]) | (f2bf(tile[p][c8 * 8 + 1]) << 16);
      w.y = f2bf(tile[p][c8 * 8 + 2]) | (f2bf(tile[p][c8 * 8 + 3]) << 16);
      w.z = f2bf(tile[p][c8 * 8 + 4]) | (f2bf(tile[p][c8 * 8 + 5]) << 16);
      w.w = f2bf(tile[p][c8 * 8 + 6]) | (f2bf(tile[p][c8 * 8 + 7]) << 16);
      *(uint4*)(dst + (size_t)pp * 32 + c8 * 4) = w;
    }
  }
}

// ---------------------------------------------------------------------------
// K2: Fused projection + gather + coalesced store.
// Round-11 (vs r8 baseline; coop path deleted — r10: grid.sync = 367us):
//  - k-loop UNROLLED x2: v0+v1 extracted per iteration, 4 tap loads in
//    flight before the FMA cluster (compiler won't pipeline an unknown-trip
//    loop). FMA order preserved -> bit-identical accumulation. Odd-km
//    residue uses the zeroed dead-rec path (same invariant as r8).
//  - Phase C: float4 nontemporal stores (16B/lane instead of 4B/lane).
// ---------------------------------------------------------------------------
__global__ __launch_bounds__(256, 4) void gather_fused(
    const uint4* __restrict__ feat4,    // [V*PLANE][8] uint4 (64 bf16 ch)
    const float* __restrict__ points,
    const float* __restrict__ proj,
    float* __restrict__ out) {
  __shared__ uint2  pdl_pix[64][NV];          // 3KB  (p00|p10<<16, p01|p11<<16)
  __shared__ float4 pdl_w[64][NV];            // 6KB  (w00,w10,w01,w11) f32
  __shared__ unsigned short tile_h[64][66];   // 8.4KB f16 staging
  __shared__ unsigned int vmask[64];
  __shared__ float projl[96];

  // spatial swizzle: XCD (~bi&7) owns two 32ix x 32iy squares
  const int bi   = blockIdx.x;
  const int xcd  = bi & 7;
  const int r    = bi >> 3;
  const int tid  = xcd * 2 + (r >> 7);
  const int q    = r & 127;
  const int ix   = (tid & 3) * 32 + (q & 31);
  const int iyg  = (tid >> 2) * 4 + (q >> 5);
  const int iy0g = iyg * 8;

  const int t    = threadIdx.x;
  const int lane = t & 63;
  const int wave = t >> 6;

  if (t < 96) projl[t] = proj[t];
  if (t < 64) vmask[t] = 0u;
  __syncthreads();

  // ---- Phase A: all 256 threads; (slot, view-pair) per thread ----
  {
    const int slot = t & 63;
    const int vb   = t >> 6;
    const int j    = slot >> 3;
    const int iz   = slot & 7;
    const int n    = iz * (NXv * NYv) + (iy0g + j) * NXv + ix;

    const float x = points[n * 3 + 0];
    const float y = points[n * 3 + 1];
    const float z = points[n * 3 + 2];

#pragma unroll
    for (int vo = 0; vo < 2; ++vo) {
      const int v = vb + vo * 4;
      if (v < NV) {
        const float* M = projl + v * 16;
        const float cx = M[0] * x + M[1] * y + M[2]  * z + M[3];
        const float cy = M[4] * x + M[5] * y + M[6]  * z + M[7];
        const float cz = M[8] * x + M[9] * y + M[10] * z + M[11];

        const float dz = (fabsf(cz) > 1e-6f) ? cz : 1e-6f;
        const float u  = cx / dz;
        const float vv = cy / dz;

        const bool valid = (cz > 0.0f) && (u > 0.0f) && (u < 1600.0f) &&
                           (vv > 0.0f) && (vv < 928.0f);
        if (valid) {
          const float px = u  / 1600.0f * 200.0f - 0.5f;
          const float py = vv / 928.0f  * 116.0f - 0.5f;
          const float fx0 = floorf(px);
          const float fy0 = floorf(py);
          const float wx1 = px - fx0;
          const float wy1 = py - fy0;
          const float wx0 = 1.0f - wx1;
          const float wy0 = 1.0f - wy1;
          const int ix0 = (int)fx0;
          const int iy0 = (int)fy0;

          // per-tap in-bounds masks (reference semantics)
          const bool bx0 = (ix0 >= 0) && (ix0 < WFv);
          const bool bx1 = (ix0 + 1 >= 0) && (ix0 + 1 < WFv);
          const bool by0 = (iy0 >= 0) && (iy0 < HFv);
          const bool by1 = (iy0 + 1 >= 0) && (iy0 + 1 < HFv);

          // per-tap independently clamped coords (reference semantics)
          const int xc0 = min(max(ix0, 0), WFv - 1);
          const int xc1 = min(max(ix0 + 1, 0), WFv - 1);
          const int yc0 = min(max(iy0, 0), HFv - 1);
          const int yc1 = min(max(iy0 + 1, 0), HFv - 1);
          const unsigned int p00 = (unsigned int)(yc0 * WFv + xc0);
          const unsigned int p10 = (unsigned int)(yc0 * WFv + xc1);
          const unsigned int p01 = (unsigned int)(yc1 * WFv + xc0);
          const unsigned int p11 = (unsigned int)(yc1 * WFv + xc1);

          uint2 pix;
          pix.x = p00 | (p10 << 16);
          pix.y = p01 | (p11 << 16);
          float4 wv;
          wv.x = (bx0 && by0) ? wx0 * wy0 : 0.0f;
          wv.y = (bx1 && by0) ? wx1 * wy0 : 0.0f;
          wv.z = (bx0 && by1) ? wx0 * wy1 : 0.0f;
          wv.w = (bx1 && by1) ? wx1 * wy1 : 0.0f;
          pdl_pix[slot][v] = pix;
          pdl_w[slot][v]   = wv;
          atomicOr(&vmask[slot], 1u << v);
        } else {
          pdl_pix[slot][v] = (uint2){0u, 0u};
          pdl_w[slot][v]   = (float4){0.0f, 0.0f, 0.0f, 0.0f};
        }
      }
    }
  }
  __syncthreads();

  // ---- Phase B: tap-split branchless gather, k-loop unrolled x2 ----
  // lane = pg2(2b) | ch(3b) | half(1b):  4 points x 8 ch-chunks x 2 halves
  const int pg2  = lane >> 4;        // point within group of 4
  const int ch   = (lane >> 1) & 7;  // uint4 chunk (8 channels)
  const int half = lane & 1;         // 0: taps (p00,p10)  1: taps (p01,p11)

#pragma unroll
  for (int i = 0; i < 4; ++i) {
    const int gi = wave * 4 + i;     // 0..15
    const int jg = gi >> 3;          // 0..1
    const int iz = gi & 7;
    const int sl = (jg * 4 + pg2) * 8 + iz;   // same-z, adjacent-j group of 4

    const unsigned int m0 = vmask[sl];
    const int mycnt = __popc(m0);
    const int vdead = min(__builtin_ctz(~m0), NV - 1);

    int km = mycnt;
    km = max(km, __shfl_xor(km, 16));
    km = max(km, __shfl_xor(km, 32));   // wave-uniform max over the 4 points

    v2f acc2[4];
#pragma unroll
    for (int j2 = 0; j2 < 4; ++j2) acc2[j2] = (v2f){0.0f, 0.0f};

    unsigned int m = m0;
    for (int k = 0; k < km; k += 2) {
      const bool live0 = (k < mycnt);
      const int v0 = live0 ? __builtin_ctz(m | 0x40u) : vdead;
      m &= m - 1;
      const bool live1 = (k + 1 < mycnt);
      const int v1 = live1 ? __builtin_ctz(m | 0x40u) : vdead;
      m &= m - 1;

      const uint2 pix0 = pdl_pix[sl][v0];
      const uint2 pix1 = pdl_pix[sl][v1];
      const unsigned int ui0 = half ? pix0.y : pix0.x;
      const unsigned int ui1 = half ? pix1.y : pix1.x;
      const v2f wp0 = *((const v2f*)&pdl_w[sl][v0] + half);
      const v2f wp1 = *((const v2f*)&pdl_w[sl][v1] + half);

      const uint4* fb0 = feat4 + (size_t)v0 * (PLANE * 8) + ch;
      const uint4* fb1 = feat4 + (size_t)v1 * (PLANE * 8) + ch;
      const uint4 qa0 = fb0[(size_t)(ui0 & 0xffffu) * 8];
      const uint4 qb0 = fb0[(size_t)(ui0 >> 16) * 8];
      const uint4 qa1 = fb1[(size_t)(ui1 & 0xffffu) * 8];
      const uint4 qb1 = fb1[(size_t)(ui1 >> 16) * 8];

      const v2f wva0 = (v2f){wp0.x, wp0.x};
      const v2f wvb0 = (v2f){wp0.y, wp0.y};
      const v2f wva1 = (v2f){wp1.x, wp1.x};
      const v2f wvb1 = (v2f){wp1.y, wp1.y};

      acc2[0] = __builtin_elementwise_fma(wva0, bfpair(qa0.x), acc2[0]);
      acc2[1] = __builtin_elementwise_fma(wva0, bfpair(qa0.y), acc2[1]);
      acc2[2] = __builtin_elementwise_fma(wva0, bfpair(qa0.z), acc2[2]);
      acc2[3] = __builtin_elementwise_fma(wva0, bfpair(qa0.w), acc2[3]);

      acc2[0] = __builtin_elementwise_fma(wvb0, bfpair(qb0.x), acc2[0]);
      acc2[1] = __builtin_elementwise_fma(wvb0, bfpair(qb0.y), acc2[1]);
      acc2[2] = __builtin_elementwise_fma(wvb0, bfpair(qb0.z), acc2[2]);
      acc2[3] = __builtin_elementwise_fma(wvb0, bfpair(qb0.w), acc2[3]);

      acc2[0] = __builtin_elementwise_fma(wva1, bfpair(qa1.x), acc2[0]);
      acc2[1] = __builtin_elementwise_fma(wva1, bfpair(qa1.y), acc2[1]);
      acc2[2] = __builtin_elementwise_fma(wva1, bfpair(qa1.z), acc2[2]);
      acc2[3] = __builtin_elementwise_fma(wva1, bfpair(qa1.w), acc2[3]);

      acc2[0] = __builtin_elementwise_fma(wvb1, bfpair(qb1.x), acc2[0]);
      acc2[1] = __builtin_elementwise_fma(wvb1, bfpair(qb1.y), acc2[1]);
      acc2[2] = __builtin_elementwise_fma(wvb1, bfpair(qb1.z), acc2[2]);
      acc2[3] = __builtin_elementwise_fma(wvb1, bfpair(qb1.w), acc2[3]);
    }

    // merge tap-halves: partner lane = lane ^ 1
#pragma unroll
    for (int j2 = 0; j2 < 4; ++j2) {
      acc2[j2].x += __shfl_xor(acc2[j2].x, 1);
      acc2[j2].y += __shfl_xor(acc2[j2].y, 1);
    }

    if (half == 0) {
      const float inv = (mycnt > 0) ? 1.0f / (float)mycnt : 0.0f;
#pragma unroll
      for (int j2 = 0; j2 < 4; ++j2) {
        const unsigned int pk =
            (unsigned int)f2h_bits(acc2[j2].x * inv) |
            ((unsigned int)f2h_bits(acc2[j2].y * inv) << 16);
        *(unsigned int*)&tile_h[sl][ch * 8 + j2 * 2] = pk;
      }
    }
  }

  __syncthreads();

  // ---- Phase C: float4 nontemporal coalesced store ----
  // 256 threads = 16 channels x 16 float4-slots per iteration, 4 iterations.
  const size_t blockbase = (size_t)ix * (NYv * NZv) + (size_t)iy0g * NZv;
  const int q4 = t & 15;           // float4 slot within the 64-float run
  const int cb = t >> 4;           // 0..15
#pragma unroll
  for (int i = 0; i < 4; ++i) {
    const int c = i * 16 + cb;
    v4f vf;
    vf.x = h_bits2f(tile_h[q4 * 4 + 0][c]);
    vf.y = h_bits2f(tile_h[q4 * 4 + 1][c]);
    vf.z = h_bits2f(tile_h[q4 * 4 + 2][c]);
    vf.w = h_bits2f(tile_h[q4 * 4 + 3][c]);
    __builtin_nontemporal_store(vf, (v4f*)(out + (size_t)c * NVOX + blockbase + q4 * 4));
  }
}

// ---------------------------------------------------------------------------
// Fallback: direct channel-major sampling (no workspace).
// ---------------------------------------------------------------------------
__global__ __launch_bounds__(256) void sample_fallback(
    const float* __restrict__ feat,
    const float* __restrict__ points,
    const float* __restrict__ proj,
    float* __restrict__ out) {
  const int wave = threadIdx.x >> 6;
  const int lane = threadIdx.x & 63;
  const int n = blockIdx.x * 4 + wave;

  const float x = points[n * 3 + 0];
  const float y = points[n * 3 + 1];
  const float z = points[n * 3 + 2];

  float acc = 0.0f;
  int cnt = 0;

#pragma unroll
  for (int v = 0; v < NV; ++v) {
    const float* M = proj + v * 16;
    const float cx = M[0] * x + M[1] * y + M[2]  * z + M[3];
    const float cy = M[4] * x + M[5] * y + M[6]  * z + M[7];
    const float cz = M[8] * x + M[9] * y + M[10] * z + M[11];
    const float dz = (fabsf(cz) > 1e-6f) ? cz : 1e-6f;
    const float u  = cx / dz;
    const float vv = cy / dz;
    const bool valid = (cz > 0.0f) && (u > 0.0f) && (u < 1600.0f) &&
                       (vv > 0.0f) && (vv < 928.0f);
    if (!valid) continue;
    cnt++;
    const float px = u  / 1600.0f * 200.0f - 0.5f;
    const float py = vv / 928.0f  * 116.0f - 0.5f;
    const float fx0 = floorf(px);
    const float fy0 = floorf(py);
    const float wx1 = px - fx0;
    const float wy1 = py - fy0;
    const float wx0 = 1.0f - wx1;
    const float wy0 = 1.0f - wy1;
    const int ix0 = (int)fx0;
    const int iy0 = (int)fy0;
    const float w00 = wx0 * wy0, w10 = wx1 * wy0, w01 = wx0 * wy1, w11 = wx1 * wy1;
    const float* basev = feat + ((size_t)v * NC + lane) * PLANE;
    auto tap = [&](int xi, int yi, float w) {
      if (xi >= 0 && xi < WFv && yi >= 0 && yi < HFv)
        acc += w * basev[yi * WFv + xi];
    };
    tap(ix0,     iy0,     w00);
    tap(ix0 + 1, iy0,     w10);
    tap(ix0,     iy0 + 1, w01);
    tap(ix0 + 1, iy0 + 1, w11);
  }

  const float scale = (cnt > 0) ? (1.0f / (float)cnt) : 0.0f;
  const int iz  = n >> 14;
  const int rem = n & 16383;
  const int iy  = rem >> 7;
  const int ixx = rem & 127;
  out[(((size_t)lane * NXv + ixx) * NYv + iy) * NZv + iz] = acc * scale;
}

extern "C" void kernel_launch(void* const* d_in, const int* in_sizes, int n_in,
                              void* d_out, int out_size, void* d_ws, size_t ws_size,
                              hipStream_t stream) {
  const float* x_fov  = (const float*)d_in[0];  // [1,6,64,116,200] f32
  const float* points = (const float*)d_in[1];  // [131072,3] f32
  const float* proj   = (const float*)d_in[2];  // [6,4,4] f32
  float* out = (float*)d_out;                   // [1,64,128,128,8] f32

  if (ws_size >= FT_BYTES) {
    unsigned int* ft = (unsigned int*)d_ws;
    dim3 tgrid((PLANE + 63) / 64, NV);
    transpose_feat_bf16<<<tgrid, 256, 0, stream>>>(x_fov, ft);
    gather_fused<<<NXv * NYv / 8, 256, 0, stream>>>((const uint4*)ft, points, proj, out);
  } else {
    sample_fallback<<<NVOX / 4, 256, 0, stream>>>(x_fov, points, proj, out);
  }
}